// Round 17
// baseline (412.935 us; speedup 1.0000x reference)
//
#include <hip/hip_runtime.h>
#include <hip/hip_bf16.h>

// Problem constants
#define BB 8
#define CC 64
#define OO 128
#define HH 128
#define WW 128
#define HW (HH*WW)         // 16384
#define NTAP 9

typedef float f32x4 __attribute__((ext_vector_type(4)));
typedef short short8 __attribute__((ext_vector_type(8)));

__device__ __forceinline__ uint f2bf(float v) {
    uint b = __float_as_uint(v);
    return (b + 0x7FFFu + ((b >> 16) & 1u)) >> 16;   // RNE to bf16
}

__device__ __forceinline__ float sampf(const float* __restrict__ xc, int iy, int ix) {
    // padded-image coords (130x130, zero border of width 1)
    unsigned uy = (unsigned)(iy - 1), ux = (unsigned)(ix - 1);
    return (uy < 128u && ux < 128u) ? xc[uy * 128 + ux] : 0.f;
}

// ---------------------------------------------------------------------------
// Kernel 0: repack weights (validated verbatim).
// ---------------------------------------------------------------------------
__global__ void k_repack(const float* __restrict__ pw, const float* __restrict__ dw,
                         const float* __restrict__ cw,
                         float* __restrict__ wp1, float* __restrict__ wpd,
                         ushort* __restrict__ wb2) {
    int i = blockIdx.x * 256 + threadIdx.x;
    if (i < 10368) {
        int o = i % 18, t = (i / 18) % 9, c = i / 162;
        wp1[i] = pw[(o * 64 + c) * 9 + t];
    }
    if (i < 36864) {
        int o = i % 64, t = (i / 64) % 9, c = i / 576;
        wpd[i] = dw[(o * 64 + c) * 9 + t];
    }
    if (i < 73728) {
        int j = i & 7, lane = (i >> 3) & 63, ot = (i >> 9) & 7;
        int kc = (i >> 12) & 1, t = i >> 13;
        int c = kc * 32 + (lane >> 4) * 8 + j;
        int oc = ot * 16 + (lane & 15);
        wb2[i] = (ushort)f2bf(cw[(oc * 64 + c) * 9 + t]);
    }
}

// ---------------------------------------------------------------------------
// Kernel 1: p_conv — occupancy rewrite v2. 8x8 tiles -> 2048 blocks
// (7 blocks/CU by LDS, 28 waves = 87%). 256 threads = 64 px x 4 wave-
// quarters (q = readfirstlane -> weight rows stay on the scalar path,
// R16 lesson). 16-ch LDS chunks; deterministic 3-buffer reduction.
// LDS = 6400 + 14592 = 20992 B.
// ---------------------------------------------------------------------------
__global__ __launch_bounds__(256) void k_pconv(const float* __restrict__ x,
                                               const float* __restrict__ wp1,
                                               const float* __restrict__ pb,
                                               float* __restrict__ off) {
    int tile = blockIdx.x;                 // 0..255 (16x16 tiles of 8x8)
    int b = blockIdx.y;
    int ty0 = (tile >> 4) * 8, tx0 = (tile & 15) * 8;
    int tid = threadIdx.x;
    int px = tid & 63;                     // pixel 0..63
    int q = __builtin_amdgcn_readfirstlane(tid >> 6);  // wave quarter 0..3
    int pyr = px >> 3, pxl = px & 7;

    __shared__ float lx[16][100];          // 16 ch x (10x10) halo
    __shared__ float pacc[3][64][19];      // partials from quarters 1..3

    float acc[18];
#pragma unroll
    for (int o = 0; o < 18; o++) acc[o] = 0.f;

    for (int h = 0; h < 4; h++) {
        __syncthreads();                   // lx reuse
        for (int idx = tid; idx < 1600; idx += 256) {
            int c = idx / 100, pos = idx % 100;
            int r = pos / 10, col = pos % 10;
            int gy = ty0 + r - 1, gx = tx0 + col - 1;
            float v = 0.f;
            if ((unsigned)gy < 128u && (unsigned)gx < 128u)
                v = x[((b * 64 + h * 16 + c) * 128 + gy) * 128 + gx];
            lx[c][pos] = v;
        }
        __syncthreads();
        for (int ci = 0; ci < 4; ci++) {
            int c = q * 4 + ci;            // chunk-local channel (wave-uniform)
#pragma unroll
            for (int t = 0; t < 9; t++) {
                float xv = lx[c][(pyr + t / 3) * 10 + pxl + t % 3];
                const float* wr = wp1 + ((h * 16 + c) * 9 + t) * 18;  // s_load
#pragma unroll
                for (int o = 0; o < 18; o++) acc[o] = fmaf(xv, wr[o], acc[o]);
            }
        }
    }
    // ---- deterministic reduction: quarters 1..3 -> LDS, quarter 0 sums ----
    if (q) {
#pragma unroll
        for (int o = 0; o < 18; o++) pacc[q - 1][px][o] = acc[o];
    }
    __syncthreads();
    if (q == 0) {
        int yy = ty0 + pyr, xx = tx0 + pxl;
#pragma unroll
        for (int o = 0; o < 18; o++)
            off[((b * 18 + o) * 128 + yy) * 128 + xx] =
                acc[o] + pacc[0][px][o] + pacc[1][px][o] + pacc[2][px][o] + pb[o];
    }
}

// ---------------------------------------------------------------------------
// Kernel 2: deformable conv fp32 — R14/R16-validated verbatim.
// ---------------------------------------------------------------------------
__global__ __launch_bounds__(256) void k_deform(const float* __restrict__ x,
                                                const float* __restrict__ off,
                                                const float* __restrict__ wpd,
                                                float* __restrict__ y) {
    int tile = blockIdx.x;                 // 0..255
    int b = blockIdx.y;
    int ty0 = (tile / 16) * 8, tx0 = (tile % 16) * 8;
    int tid = threadIdx.x;

    __shared__ uint   mwin[576];           // packed window offsets; 0xFFFFFFFF = fallback
    __shared__ float4 mwt[576];            // bilinear weights (OOB corners zeroed)
    __shared__ uint   xtile[4 * 256];      // [pair][pos] bf16 c-pairs, window = tile +/- 4
    __shared__ uint   xo[4][580];          // [pair][tap*64+px] bf16 c-pairs

    // ---- Stage A: bilinear metadata (R2/R9/R11-proven math) ----
    for (int e = tid; e < 576; e += 256) {
        int n = e >> 6, p = e & 63;
        int py = p >> 3, px = p & 7;
        int yy = ty0 + py, xx = tx0 + px;
        float offh = off[((b * 18 + n) * 128 + yy) * 128 + xx];
        float offw = off[((b * 18 + 9 + n) * 128 + yy) * 128 + xx];
        float ph = (float)(yy + 1) + (float)(n / 3 - 1) + offh;
        float pw = (float)(xx + 1) + (float)(n % 3 - 1) + offw;
        ph = fminf(fmaxf(ph, 0.f), 129.f);
        pw = fminf(fmaxf(pw, 0.f), 129.f);
        float fh = floorf(ph), fw = floorf(pw);
        int lth = (int)fh, ltw = (int)fw;
        int rbh = min(lth + 1, 129), rbw = min(ltw + 1, 129);
        float dh_l = 1.f + (fh - ph);
        float dh_r = 1.f - ((float)rbh - ph);
        float dw_l = 1.f + (fw - pw);
        float dw_r = 1.f - ((float)rbw - pw);
        int uy0 = lth - 1, ux0 = ltw - 1, uy1 = rbh - 1, ux1 = rbw - 1;
        bool iy0 = (unsigned)uy0 < 128u, ix0 = (unsigned)ux0 < 128u;
        bool iy1 = (unsigned)uy1 < 128u, ix1 = (unsigned)ux1 < 128u;
        float w_lt = (iy0 && ix0) ? dh_l * dw_l : 0.f;
        float w_rb = (iy1 && ix1) ? dh_r * dw_r : 0.f;
        float w_lb = (iy0 && ix1) ? dh_l * dw_r : 0.f;
        float w_rt = (iy1 && ix0) ? dh_r * dw_l : 0.f;
        mwt[e] = make_float4(w_lt, w_rb, w_lb, w_rt);
        int wy0 = uy0 - ty0 + 4, wx0 = ux0 - tx0 + 4;
        int wy1 = uy1 - ty0 + 4, wx1 = ux1 - tx0 + 4;
        uint win = 0xFFFFFFFFu;
        if ((unsigned)wy0 < 16u && (unsigned)wx0 < 16u &&
            (unsigned)wy1 < 16u && (unsigned)wx1 < 16u) {
            uint o00 = (uint)(wy0 * 16 + wx0);
            uint o11 = (uint)(wy1 * 16 + wx1);
            uint o01 = (uint)(wy0 * 16 + wx1);
            uint o10 = (uint)(wy1 * 16 + wx0);
            win = o00 | (o11 << 8) | (o01 << 16) | (o10 << 24);
        }
        mwin[e] = win;
    }

    float acc[16] = {};
    int cg = tid >> 6;                     // wave id = channel-PAIR in gather
    int l64 = tid & 63;                    // lane = pixel in contraction
    int cgoff = cg * 256;
    int ob = __builtin_amdgcn_readfirstlane(cg * 16);  // wave's oc base

    // staging coords for this thread (position = tid)
    int sgy = ty0 - 4 + (tid >> 4), sgx = tx0 - 4 + (tid & 15);
    bool sinb = ((unsigned)sgy < 128u && (unsigned)sgx < 128u);
    int spos = sgy * 128 + sgx;

    for (int cc = 0; cc < 8; cc++) {
        // ---- stage 16x16 window, 8 channels packed as 4 bf16-pairs ----
#pragma unroll
        for (int q = 0; q < 4; q++) {
            int c0 = cc * 8 + 2 * q;
            float v0 = 0.f, v1 = 0.f;
            if (sinb) {
                v0 = x[(size_t)(b * 64 + c0) * HW + spos];
                v1 = x[(size_t)(b * 64 + c0 + 1) * HW + spos];
            }
            xtile[q * 256 + tid] = (f2bf(v1) << 16) | f2bf(v0);
        }
        __syncthreads();                   // xtile staged (prev phases closed)
        // ---- gather: 4 random b32 reads serve 2 channels each ----
#pragma unroll 2
        for (int i = 0; i < 9; i++) {
            int e = l64 + 64 * i;
            uint w = mwin[e];
            float4 g = mwt[e];
            float vlo, vhi;
            if (__builtin_expect(w != 0xFFFFFFFFu, 1)) {
                uint u00 = xtile[cgoff + (w & 255u)];
                uint u11 = xtile[cgoff + ((w >> 8) & 255u)];
                uint u01 = xtile[cgoff + ((w >> 16) & 255u)];
                uint u10 = xtile[cgoff + (w >> 24)];
                float a00l = __uint_as_float(u00 << 16), a00h = __uint_as_float(u00 & 0xFFFF0000u);
                float a11l = __uint_as_float(u11 << 16), a11h = __uint_as_float(u11 & 0xFFFF0000u);
                float a01l = __uint_as_float(u01 << 16), a01h = __uint_as_float(u01 & 0xFFFF0000u);
                float a10l = __uint_as_float(u10 << 16), a10h = __uint_as_float(u10 & 0xFFFF0000u);
                vlo = g.x * a00l + g.y * a11l + g.z * a01l + g.w * a10l;
                vhi = g.x * a00h + g.y * a11h + g.z * a01h + g.w * a10h;
            } else {
                // cold fallback: exact R2 global path for both channels
                int n = e >> 6, p = e & 63;
                int yy2 = ty0 + (p >> 3), xx2 = tx0 + (p & 7);
                float offh = off[((b * 18 + n) * 128 + yy2) * 128 + xx2];
                float offw = off[((b * 18 + 9 + n) * 128 + yy2) * 128 + xx2];
                float ph = fminf(fmaxf((float)(yy2 + 1) + (float)(n / 3 - 1) + offh, 0.f), 129.f);
                float pw = fminf(fmaxf((float)(xx2 + 1) + (float)(n % 3 - 1) + offw, 0.f), 129.f);
                int lth = (int)floorf(ph), ltw = (int)floorf(pw);
                int rbh = min(lth + 1, 129), rbw = min(ltw + 1, 129);
                const float* xc0 = x + (size_t)(b * 64 + cc * 8 + 2 * cg) * HW;
                const float* xc1 = xc0 + HW;
                vlo = g.x * sampf(xc0, lth, ltw) + g.y * sampf(xc0, rbh, rbw)
                    + g.z * sampf(xc0, lth, rbw) + g.w * sampf(xc0, rbh, ltw);
                vhi = g.x * sampf(xc1, lth, ltw) + g.y * sampf(xc1, rbh, rbw)
                    + g.z * sampf(xc1, lth, rbw) + g.w * sampf(xc1, rbh, ltw);
            }
            xo[cg][e] = (f2bf(vhi) << 16) | f2bf(vlo);
        }
        __syncthreads();                   // xo ready
        // ---- contraction: one dword read -> 2 channels x 16 oc FMAs ----
        for (int q = 0; q < 4; q++) {
#pragma unroll
            for (int n = 0; n < 9; n++) {
                uint u = xo[q][n * 64 + l64];
                float xlo = __uint_as_float(u << 16);
                float xhi = __uint_as_float(u & 0xFFFF0000u);
                const float* w0 = wpd + (((cc * 8 + 2 * q) * 9 + n) * 64) + ob;
                const float* w1 = w0 + 576;   // next channel's row
#pragma unroll
                for (int j = 0; j < 16; j++) acc[j] = fmaf(xlo, w0[j], acc[j]);
#pragma unroll
                for (int j = 0; j < 16; j++) acc[j] = fmaf(xhi, w1[j], acc[j]);
            }
        }
        __syncthreads();                   // contraction done before next stage
    }

    // ---- epilogue: direct per-lane stores (lane=pixel, wave's 16 oc) ----
    int yy = ty0 + (l64 >> 3), xx = tx0 + (l64 & 7);
#pragma unroll
    for (int j = 0; j < 16; j++)
        y[(size_t)(b * 64 + ob + j) * HW + yy * 128 + xx] = acc[j];
}

// ---------------------------------------------------------------------------
// Kernel 3a/3b: BN statistics. bnpart now splits HW into 4 quarters
// (grid 64x32 = 2048 blocks, was 512) for full-BW read; bnfinal sums the
// 32 partials per channel in fixed order (deterministic).
// ---------------------------------------------------------------------------
__global__ __launch_bounds__(256) void k_bnpart(const float* __restrict__ y,
                                                float* __restrict__ part) {
    int c = blockIdx.x;                    // 0..63
    int bq = blockIdx.y;                   // 0..31
    int b = bq >> 2, hq = bq & 3;
    int tid = threadIdx.x;
    const float4* p = (const float4*)(y + (size_t)(b * 64 + c) * HW + hq * 4096);
    float s = 0.f, sq = 0.f;
    for (int i = tid; i < 1024; i += 256) {
        float4 v = p[i];
        s += v.x + v.y + v.z + v.w;
        sq += v.x * v.x + v.y * v.y + v.z * v.z + v.w * v.w;
    }
#pragma unroll
    for (int o = 32; o > 0; o >>= 1) {
        s += __shfl_down(s, o);
        sq += __shfl_down(sq, o);
    }
    __shared__ float rs[4], rq[4];
    int wid = tid >> 6;
    if ((tid & 63) == 0) { rs[wid] = s; rq[wid] = sq; }
    __syncthreads();
    if (tid == 0) {
        part[((b * 64 + c) * 4 + hq) * 2]     = rs[0] + rs[1] + rs[2] + rs[3];
        part[((b * 64 + c) * 4 + hq) * 2 + 1] = rq[0] + rq[1] + rq[2] + rq[3];
    }
}

__global__ void k_bnfinal(const float* __restrict__ part,
                          const float* __restrict__ gamma,
                          const float* __restrict__ beta,
                          float* __restrict__ ss) {
    int c = threadIdx.x;                   // 64 threads
    float s = 0.f, sq = 0.f;
#pragma unroll
    for (int b = 0; b < 8; b++)
#pragma unroll
        for (int hq = 0; hq < 4; hq++) {
            s += part[((b * 64 + c) * 4 + hq) * 2];
            sq += part[((b * 64 + c) * 4 + hq) * 2 + 1];
        }
    const float inv = 1.f / (float)(8 * HW);
    float mean = s * inv;
    float var = sq * inv - mean * mean;
    float scale = gamma[c] * rsqrtf(var + 1e-5f);
    ss[c] = scale;
    ss[64 + c] = beta[c] - mean * scale;
}

// ---------------------------------------------------------------------------
// Kernel 4: conv2 via MFMA — validated verbatim.
// ---------------------------------------------------------------------------
__global__ __launch_bounds__(256) void k_conv2(const float* __restrict__ x,
                                               const float* __restrict__ y,
                                               const float* __restrict__ ss,
                                               const ushort* __restrict__ wb2,
                                               const float* __restrict__ b2,
                                               float* __restrict__ out) {
    int tile = blockIdx.x, b = blockIdx.y;
    int ty0 = (tile / 16) * 8, tx0 = (tile % 16) * 8;
    int tid = threadIdx.x;

    __shared__ uint lz[3600];              // [100 pos][36 dwords] bf16 c-pairs

    for (int idx = tid; idx < 3200; idx += 256) {
        int q = idx / 100, pos = idx % 100;
        int r = pos / 10, col = pos % 10;
        int gy = ty0 + r - 1, gx = tx0 + col - 1;
        uint u = 0;
        if ((unsigned)gy < 128u && (unsigned)gx < 128u) {
            int c0 = q * 2;
            int gi = ((b * 64 + c0) * HW) + gy * 128 + gx;
            float t0 = fmaf(y[gi], ss[c0], ss[64 + c0]);
            float v0 = fmaxf(t0, 0.f) + x[gi];
            float t1 = fmaf(y[gi + HW], ss[c0 + 1], ss[65 + c0]);
            float v1 = fmaxf(t1, 0.f) + x[gi + HW];
            u = (f2bf(v1) << 16) | f2bf(v0);
        }
        lz[pos * 36 + q] = u;
    }
    __syncthreads();

    int lane = tid & 63, pg = tid >> 6;
    int r16 = lane & 15, jg = lane >> 4;
    int p = pg * 16 + r16;
    int pyA = p >> 3, pxA = p & 7;

    f32x4 acc[8];
#pragma unroll
    for (int ot = 0; ot < 8; ot++) {
        float bv = b2[ot * 16 + r16];
        acc[ot] = (f32x4){bv, bv, bv, bv};
    }

#pragma unroll
    for (int t = 0; t < 9; t++) {
        int pos = (pyA + t / 3) * 10 + (pxA + t % 3);
#pragma unroll
        for (int kc = 0; kc < 2; kc++) {
            short8 av = *(const short8*)(lz + pos * 36 + kc * 16 + jg * 4);
            const ushort* wk = wb2 + (t * 2 + kc) * 4096 + lane * 8;
#pragma unroll
            for (int ot = 0; ot < 8; ot++) {
                short8 bv = *(const short8*)(wk + ot * 512);
                acc[ot] = __builtin_amdgcn_mfma_f32_16x16x32_bf16(av, bv, acc[ot], 0, 0, 0);
            }
        }
    }

    // ---- epilogue: direct per-lane vector stores ----
    int p0 = pg * 16 + jg * 4;
    int yy = ty0 + (p0 >> 3), xx = tx0 + (p0 & 7);
#pragma unroll
    for (int ot = 0; ot < 8; ot++) {
        int oc = ot * 16 + r16;
        *(f32x4*)(out + (size_t)(b * 128 + oc) * HW + yy * 128 + xx) = acc[ot];
    }
}

// ---------------------------------------------------------------------------
extern "C" void kernel_launch(void* const* d_in, const int* in_sizes, int n_in,
                              void* d_out, int out_size, void* d_ws, size_t ws_size,
                              hipStream_t stream) {
    const float* x     = (const float*)d_in[0];
    const float* pw    = (const float*)d_in[1];
    const float* pb    = (const float*)d_in[2];
    const float* dw    = (const float*)d_in[3];
    const float* gamma = (const float*)d_in[4];
    const float* beta  = (const float*)d_in[5];
    const float* cw    = (const float*)d_in[6];
    const float* cb    = (const float*)d_in[7];
    float* out = (float*)d_out;
    float* ws  = (float*)d_ws;

    // workspace layout (float offsets)
    float*  wp1  = ws;                      // 10368
    float*  ss   = ws + 10368;              // 128
    float*  part = ws + 10496;              // 4096 -> ends 14592
    float*  wpd  = ws + 14592;              // 36864 -> ends 51456
    ushort* wb2  = (ushort*)(ws + 51456);   // 73728 sh (36864 f) -> ends 88320
    float*  off  = ws + 88320;              // 2359296 -> ends 2447616
    float*  yb   = ws + 2447616;            // 8388608 -> ends 10836224
    // total: 10836224 floats = 43.3 MB

    k_repack<<<dim3(288), dim3(256), 0, stream>>>(pw, dw, cw, wp1, wpd, wb2);
    k_pconv<<<dim3(256, 8), dim3(256), 0, stream>>>(x, wp1, pb, off);
    k_deform<<<dim3(256, 8), dim3(256), 0, stream>>>(x, off, wpd, yb);
    k_bnpart<<<dim3(64, 32), dim3(256), 0, stream>>>(yb, part);
    k_bnfinal<<<dim3(1), dim3(64), 0, stream>>>(part, gamma, beta, ss);
    k_conv2<<<dim3(256, 8), dim3(256), 0, stream>>>(x, yb, ss, wb2, cb, out);
}

// Round 18
// 319.119 us; speedup vs baseline: 1.2940x; 1.2940x over previous
//
#include <hip/hip_runtime.h>
#include <hip/hip_bf16.h>

// Problem constants
#define BB 8
#define CC 64
#define OO 128
#define HH 128
#define WW 128
#define HW (HH*WW)         // 16384
#define NTAP 9

typedef float f32x4 __attribute__((ext_vector_type(4)));
typedef short short8 __attribute__((ext_vector_type(8)));

__device__ __forceinline__ uint f2bf(float v) {
    uint b = __float_as_uint(v);
    return (b + 0x7FFFu + ((b >> 16) & 1u)) >> 16;   // RNE to bf16
}

__device__ __forceinline__ float sampf(const float* __restrict__ xc, int iy, int ix) {
    // padded-image coords (130x130, zero border of width 1)
    unsigned uy = (unsigned)(iy - 1), ux = (unsigned)(ix - 1);
    return (uy < 128u && ux < 128u) ? xc[uy * 128 + ux] : 0.f;
}

// ---------------------------------------------------------------------------
// Kernel 0: repack weights (validated verbatim).
// ---------------------------------------------------------------------------
__global__ void k_repack(const float* __restrict__ pw, const float* __restrict__ dw,
                         const float* __restrict__ cw,
                         float* __restrict__ wp1, float* __restrict__ wpd,
                         ushort* __restrict__ wb2) {
    int i = blockIdx.x * 256 + threadIdx.x;
    if (i < 10368) {
        int o = i % 18, t = (i / 18) % 9, c = i / 162;
        wp1[i] = pw[(o * 64 + c) * 9 + t];
    }
    if (i < 36864) {
        int o = i % 64, t = (i / 64) % 9, c = i / 576;
        wpd[i] = dw[(o * 64 + c) * 9 + t];
    }
    if (i < 73728) {
        int j = i & 7, lane = (i >> 3) & 63, ot = (i >> 9) & 7;
        int kc = (i >> 12) & 1, t = i >> 13;
        int c = kc * 32 + (lane >> 4) * 8 + j;
        int oc = ot * 16 + (lane & 15);
        wb2[i] = (ushort)f2bf(cw[(oc * 64 + c) * 9 + t]);
    }
}

// ---------------------------------------------------------------------------
// Kernel 1: p_conv — R16-VALIDATED VERBATIM (the R17 8x8 rewrite regressed:
// 40B staging segments + 2x barriers; this 16-wide-tile version measured
// ~60us inside the 320us R16 total). ch = readfirstlane -> s_load weights.
// ---------------------------------------------------------------------------
__global__ __launch_bounds__(256) void k_pconv(const float* __restrict__ x,
                                               const float* __restrict__ wp1,
                                               const float* __restrict__ pb,
                                               float* __restrict__ off) {
    int tile = blockIdx.x;                 // 0..127 (16 tile-rows x 8 tile-cols)
    int b = blockIdx.y;
    int ty0 = (tile >> 3) * 8, tx0 = (tile & 7) * 16;
    int tid = threadIdx.x;
    int px = tid & 127;                    // pixel 0..127
    int ch = __builtin_amdgcn_readfirstlane(tid >> 7);  // wave-uniform half 0/1
    int pyr = px >> 4, pxl = px & 15;      // 8 rows x 16 cols

    __shared__ float lx[32][180];          // 32 ch x (10 rows x 18 cols) halo
    __shared__ float pacc[128][19];        // partial acc (padded stride)

    float acc[18];
#pragma unroll
    for (int o = 0; o < 18; o++) acc[o] = 0.f;

    for (int h = 0; h < 2; h++) {
        __syncthreads();                   // h=1: lx free (all reads done)
        for (int idx = tid; idx < 5760; idx += 256) {
            int c = idx / 180, pos = idx % 180;
            int r = pos / 18, col = pos % 18;
            int gy = ty0 + r - 1, gx = tx0 + col - 1;
            float v = 0.f;
            if ((unsigned)gy < 128u && (unsigned)gx < 128u)
                v = x[((b * 64 + h * 32 + c) * 128 + gy) * 128 + gx];
            lx[c][pos] = v;
        }
        __syncthreads();
        for (int ci = 0; ci < 16; ci++) {
            int c = ch * 16 + ci;          // chunk-local channel (wave-uniform)
#pragma unroll
            for (int t = 0; t < 9; t++) {
                float xv = lx[c][(pyr + t / 3) * 18 + pxl + t % 3];
                const float* wr = wp1 + ((h * 32 + c) * 9 + t) * 18;  // s_load
#pragma unroll
                for (int o = 0; o < 18; o++) acc[o] = fmaf(xv, wr[o], acc[o]);
            }
        }
    }
    // ---- deterministic pair-reduction: ch1 -> LDS, ch0 adds + bias + store
    if (ch == 1) {
#pragma unroll
        for (int o = 0; o < 18; o++) pacc[px][o] = acc[o];
    }
    __syncthreads();
    if (ch == 0) {
        int yy = ty0 + pyr, xx = tx0 + pxl;
#pragma unroll
        for (int o = 0; o < 18; o++)
            off[((b * 18 + o) * 128 + yy) * 128 + xx] = acc[o] + pacc[px][o] + pb[o];
    }
}

// ---------------------------------------------------------------------------
// Kernel 2: deformable conv fp32 — R14/R16-validated verbatim.
// ---------------------------------------------------------------------------
__global__ __launch_bounds__(256) void k_deform(const float* __restrict__ x,
                                                const float* __restrict__ off,
                                                const float* __restrict__ wpd,
                                                float* __restrict__ y) {
    int tile = blockIdx.x;                 // 0..255
    int b = blockIdx.y;
    int ty0 = (tile / 16) * 8, tx0 = (tile % 16) * 8;
    int tid = threadIdx.x;

    __shared__ uint   mwin[576];           // packed window offsets; 0xFFFFFFFF = fallback
    __shared__ float4 mwt[576];            // bilinear weights (OOB corners zeroed)
    __shared__ uint   xtile[4 * 256];      // [pair][pos] bf16 c-pairs, window = tile +/- 4
    __shared__ uint   xo[4][580];          // [pair][tap*64+px] bf16 c-pairs

    // ---- Stage A: bilinear metadata (R2/R9/R11-proven math) ----
    for (int e = tid; e < 576; e += 256) {
        int n = e >> 6, p = e & 63;
        int py = p >> 3, px = p & 7;
        int yy = ty0 + py, xx = tx0 + px;
        float offh = off[((b * 18 + n) * 128 + yy) * 128 + xx];
        float offw = off[((b * 18 + 9 + n) * 128 + yy) * 128 + xx];
        float ph = (float)(yy + 1) + (float)(n / 3 - 1) + offh;
        float pw = (float)(xx + 1) + (float)(n % 3 - 1) + offw;
        ph = fminf(fmaxf(ph, 0.f), 129.f);
        pw = fminf(fmaxf(pw, 0.f), 129.f);
        float fh = floorf(ph), fw = floorf(pw);
        int lth = (int)fh, ltw = (int)fw;
        int rbh = min(lth + 1, 129), rbw = min(ltw + 1, 129);
        float dh_l = 1.f + (fh - ph);
        float dh_r = 1.f - ((float)rbh - ph);
        float dw_l = 1.f + (fw - pw);
        float dw_r = 1.f - ((float)rbw - pw);
        int uy0 = lth - 1, ux0 = ltw - 1, uy1 = rbh - 1, ux1 = rbw - 1;
        bool iy0 = (unsigned)uy0 < 128u, ix0 = (unsigned)ux0 < 128u;
        bool iy1 = (unsigned)uy1 < 128u, ix1 = (unsigned)ux1 < 128u;
        float w_lt = (iy0 && ix0) ? dh_l * dw_l : 0.f;
        float w_rb = (iy1 && ix1) ? dh_r * dw_r : 0.f;
        float w_lb = (iy0 && ix1) ? dh_l * dw_r : 0.f;
        float w_rt = (iy1 && ix0) ? dh_r * dw_l : 0.f;
        mwt[e] = make_float4(w_lt, w_rb, w_lb, w_rt);
        int wy0 = uy0 - ty0 + 4, wx0 = ux0 - tx0 + 4;
        int wy1 = uy1 - ty0 + 4, wx1 = ux1 - tx0 + 4;
        uint win = 0xFFFFFFFFu;
        if ((unsigned)wy0 < 16u && (unsigned)wx0 < 16u &&
            (unsigned)wy1 < 16u && (unsigned)wx1 < 16u) {
            uint o00 = (uint)(wy0 * 16 + wx0);
            uint o11 = (uint)(wy1 * 16 + wx1);
            uint o01 = (uint)(wy0 * 16 + wx1);
            uint o10 = (uint)(wy1 * 16 + wx0);
            win = o00 | (o11 << 8) | (o01 << 16) | (o10 << 24);
        }
        mwin[e] = win;
    }

    float acc[16] = {};
    int cg = tid >> 6;                     // wave id = channel-PAIR in gather
    int l64 = tid & 63;                    // lane = pixel in contraction
    int cgoff = cg * 256;
    int ob = __builtin_amdgcn_readfirstlane(cg * 16);  // wave's oc base

    // staging coords for this thread (position = tid)
    int sgy = ty0 - 4 + (tid >> 4), sgx = tx0 - 4 + (tid & 15);
    bool sinb = ((unsigned)sgy < 128u && (unsigned)sgx < 128u);
    int spos = sgy * 128 + sgx;

    for (int cc = 0; cc < 8; cc++) {
        // ---- stage 16x16 window, 8 channels packed as 4 bf16-pairs ----
#pragma unroll
        for (int q = 0; q < 4; q++) {
            int c0 = cc * 8 + 2 * q;
            float v0 = 0.f, v1 = 0.f;
            if (sinb) {
                v0 = x[(size_t)(b * 64 + c0) * HW + spos];
                v1 = x[(size_t)(b * 64 + c0 + 1) * HW + spos];
            }
            xtile[q * 256 + tid] = (f2bf(v1) << 16) | f2bf(v0);
        }
        __syncthreads();                   // xtile staged (prev phases closed)
        // ---- gather: 4 random b32 reads serve 2 channels each ----
#pragma unroll 2
        for (int i = 0; i < 9; i++) {
            int e = l64 + 64 * i;
            uint w = mwin[e];
            float4 g = mwt[e];
            float vlo, vhi;
            if (__builtin_expect(w != 0xFFFFFFFFu, 1)) {
                uint u00 = xtile[cgoff + (w & 255u)];
                uint u11 = xtile[cgoff + ((w >> 8) & 255u)];
                uint u01 = xtile[cgoff + ((w >> 16) & 255u)];
                uint u10 = xtile[cgoff + (w >> 24)];
                float a00l = __uint_as_float(u00 << 16), a00h = __uint_as_float(u00 & 0xFFFF0000u);
                float a11l = __uint_as_float(u11 << 16), a11h = __uint_as_float(u11 & 0xFFFF0000u);
                float a01l = __uint_as_float(u01 << 16), a01h = __uint_as_float(u01 & 0xFFFF0000u);
                float a10l = __uint_as_float(u10 << 16), a10h = __uint_as_float(u10 & 0xFFFF0000u);
                vlo = g.x * a00l + g.y * a11l + g.z * a01l + g.w * a10l;
                vhi = g.x * a00h + g.y * a11h + g.z * a01h + g.w * a10h;
            } else {
                // cold fallback: exact R2 global path for both channels
                int n = e >> 6, p = e & 63;
                int yy2 = ty0 + (p >> 3), xx2 = tx0 + (p & 7);
                float offh = off[((b * 18 + n) * 128 + yy2) * 128 + xx2];
                float offw = off[((b * 18 + 9 + n) * 128 + yy2) * 128 + xx2];
                float ph = fminf(fmaxf((float)(yy2 + 1) + (float)(n / 3 - 1) + offh, 0.f), 129.f);
                float pw = fminf(fmaxf((float)(xx2 + 1) + (float)(n % 3 - 1) + offw, 0.f), 129.f);
                int lth = (int)floorf(ph), ltw = (int)floorf(pw);
                int rbh = min(lth + 1, 129), rbw = min(ltw + 1, 129);
                const float* xc0 = x + (size_t)(b * 64 + cc * 8 + 2 * cg) * HW;
                const float* xc1 = xc0 + HW;
                vlo = g.x * sampf(xc0, lth, ltw) + g.y * sampf(xc0, rbh, rbw)
                    + g.z * sampf(xc0, lth, rbw) + g.w * sampf(xc0, rbh, ltw);
                vhi = g.x * sampf(xc1, lth, ltw) + g.y * sampf(xc1, rbh, rbw)
                    + g.z * sampf(xc1, lth, rbw) + g.w * sampf(xc1, rbh, ltw);
            }
            xo[cg][e] = (f2bf(vhi) << 16) | f2bf(vlo);
        }
        __syncthreads();                   // xo ready
        // ---- contraction: one dword read -> 2 channels x 16 oc FMAs ----
        for (int q = 0; q < 4; q++) {
#pragma unroll
            for (int n = 0; n < 9; n++) {
                uint u = xo[q][n * 64 + l64];
                float xlo = __uint_as_float(u << 16);
                float xhi = __uint_as_float(u & 0xFFFF0000u);
                const float* w0 = wpd + (((cc * 8 + 2 * q) * 9 + n) * 64) + ob;
                const float* w1 = w0 + 576;   // next channel's row
#pragma unroll
                for (int j = 0; j < 16; j++) acc[j] = fmaf(xlo, w0[j], acc[j]);
#pragma unroll
                for (int j = 0; j < 16; j++) acc[j] = fmaf(xhi, w1[j], acc[j]);
            }
        }
        __syncthreads();                   // contraction done before next stage
    }

    // ---- epilogue: direct per-lane stores (lane=pixel, wave's 16 oc) ----
    int yy = ty0 + (l64 >> 3), xx = tx0 + (l64 & 7);
#pragma unroll
    for (int j = 0; j < 16; j++)
        y[(size_t)(b * 64 + ob + j) * HW + yy * 128 + xx] = acc[j];
}

// ---------------------------------------------------------------------------
// Kernel 3a/3b: BN statistics — 4-quarter split (kept from R17; mechanically
// safe: 2048 blocks each streaming 16KB contiguous). bnfinal fixed-order sum.
// ---------------------------------------------------------------------------
__global__ __launch_bounds__(256) void k_bnpart(const float* __restrict__ y,
                                                float* __restrict__ part) {
    int c = blockIdx.x;                    // 0..63
    int bq = blockIdx.y;                   // 0..31
    int b = bq >> 2, hq = bq & 3;
    int tid = threadIdx.x;
    const float4* p = (const float4*)(y + (size_t)(b * 64 + c) * HW + hq * 4096);
    float s = 0.f, sq = 0.f;
    for (int i = tid; i < 1024; i += 256) {
        float4 v = p[i];
        s += v.x + v.y + v.z + v.w;
        sq += v.x * v.x + v.y * v.y + v.z * v.z + v.w * v.w;
    }
#pragma unroll
    for (int o = 32; o > 0; o >>= 1) {
        s += __shfl_down(s, o);
        sq += __shfl_down(sq, o);
    }
    __shared__ float rs[4], rq[4];
    int wid = tid >> 6;
    if ((tid & 63) == 0) { rs[wid] = s; rq[wid] = sq; }
    __syncthreads();
    if (tid == 0) {
        part[((b * 64 + c) * 4 + hq) * 2]     = rs[0] + rs[1] + rs[2] + rs[3];
        part[((b * 64 + c) * 4 + hq) * 2 + 1] = rq[0] + rq[1] + rq[2] + rq[3];
    }
}

__global__ void k_bnfinal(const float* __restrict__ part,
                          const float* __restrict__ gamma,
                          const float* __restrict__ beta,
                          float* __restrict__ ss) {
    int c = threadIdx.x;                   // 64 threads
    float s = 0.f, sq = 0.f;
#pragma unroll
    for (int b = 0; b < 8; b++)
#pragma unroll
        for (int hq = 0; hq < 4; hq++) {
            s += part[((b * 64 + c) * 4 + hq) * 2];
            sq += part[((b * 64 + c) * 4 + hq) * 2 + 1];
        }
    const float inv = 1.f / (float)(8 * HW);
    float mean = s * inv;
    float var = sq * inv - mean * mean;
    float scale = gamma[c] * rsqrtf(var + 1e-5f);
    ss[c] = scale;
    ss[64 + c] = beta[c] - mean * scale;
}

// ---------------------------------------------------------------------------
// Kernel 4: conv2 via MFMA — validated verbatim.
// ---------------------------------------------------------------------------
__global__ __launch_bounds__(256) void k_conv2(const float* __restrict__ x,
                                               const float* __restrict__ y,
                                               const float* __restrict__ ss,
                                               const ushort* __restrict__ wb2,
                                               const float* __restrict__ b2,
                                               float* __restrict__ out) {
    int tile = blockIdx.x, b = blockIdx.y;
    int ty0 = (tile / 16) * 8, tx0 = (tile % 16) * 8;
    int tid = threadIdx.x;

    __shared__ uint lz[3600];              // [100 pos][36 dwords] bf16 c-pairs

    for (int idx = tid; idx < 3200; idx += 256) {
        int q = idx / 100, pos = idx % 100;
        int r = pos / 10, col = pos % 10;
        int gy = ty0 + r - 1, gx = tx0 + col - 1;
        uint u = 0;
        if ((unsigned)gy < 128u && (unsigned)gx < 128u) {
            int c0 = q * 2;
            int gi = ((b * 64 + c0) * HW) + gy * 128 + gx;
            float t0 = fmaf(y[gi], ss[c0], ss[64 + c0]);
            float v0 = fmaxf(t0, 0.f) + x[gi];
            float t1 = fmaf(y[gi + HW], ss[c0 + 1], ss[65 + c0]);
            float v1 = fmaxf(t1, 0.f) + x[gi + HW];
            u = (f2bf(v1) << 16) | f2bf(v0);
        }
        lz[pos * 36 + q] = u;
    }
    __syncthreads();

    int lane = tid & 63, pg = tid >> 6;
    int r16 = lane & 15, jg = lane >> 4;
    int p = pg * 16 + r16;
    int pyA = p >> 3, pxA = p & 7;

    f32x4 acc[8];
#pragma unroll
    for (int ot = 0; ot < 8; ot++) {
        float bv = b2[ot * 16 + r16];
        acc[ot] = (f32x4){bv, bv, bv, bv};
    }

#pragma unroll
    for (int t = 0; t < 9; t++) {
        int pos = (pyA + t / 3) * 10 + (pxA + t % 3);
#pragma unroll
        for (int kc = 0; kc < 2; kc++) {
            short8 av = *(const short8*)(lz + pos * 36 + kc * 16 + jg * 4);
            const ushort* wk = wb2 + (t * 2 + kc) * 4096 + lane * 8;
#pragma unroll
            for (int ot = 0; ot < 8; ot++) {
                short8 bv = *(const short8*)(wk + ot * 512);
                acc[ot] = __builtin_amdgcn_mfma_f32_16x16x32_bf16(av, bv, acc[ot], 0, 0, 0);
            }
        }
    }

    // ---- epilogue: direct per-lane vector stores ----
    int p0 = pg * 16 + jg * 4;
    int yy = ty0 + (p0 >> 3), xx = tx0 + (p0 & 7);
#pragma unroll
    for (int ot = 0; ot < 8; ot++) {
        int oc = ot * 16 + r16;
        *(f32x4*)(out + (size_t)(b * 128 + oc) * HW + yy * 128 + xx) = acc[ot];
    }
}

// ---------------------------------------------------------------------------
extern "C" void kernel_launch(void* const* d_in, const int* in_sizes, int n_in,
                              void* d_out, int out_size, void* d_ws, size_t ws_size,
                              hipStream_t stream) {
    const float* x     = (const float*)d_in[0];
    const float* pw    = (const float*)d_in[1];
    const float* pb    = (const float*)d_in[2];
    const float* dw    = (const float*)d_in[3];
    const float* gamma = (const float*)d_in[4];
    const float* beta  = (const float*)d_in[5];
    const float* cw    = (const float*)d_in[6];
    const float* cb    = (const float*)d_in[7];
    float* out = (float*)d_out;
    float* ws  = (float*)d_ws;

    // workspace layout (float offsets)
    float*  wp1  = ws;                      // 10368
    float*  ss   = ws + 10368;              // 128
    float*  part = ws + 10496;              // 4096 -> ends 14592
    float*  wpd  = ws + 14592;              // 36864 -> ends 51456
    ushort* wb2  = (ushort*)(ws + 51456);   // 73728 sh (36864 f) -> ends 88320
    float*  off  = ws + 88320;              // 2359296 -> ends 2447616
    float*  yb   = ws + 2447616;            // 8388608 -> ends 10836224
    // total: 10836224 floats = 43.3 MB

    k_repack<<<dim3(288), dim3(256), 0, stream>>>(pw, dw, cw, wp1, wpd, wb2);
    k_pconv<<<dim3(128, 8), dim3(256), 0, stream>>>(x, wp1, pb, off);
    k_deform<<<dim3(256, 8), dim3(256), 0, stream>>>(x, off, wpd, yb);
    k_bnpart<<<dim3(64, 32), dim3(256), 0, stream>>>(yb, part);
    k_bnfinal<<<dim3(1), dim3(64), 0, stream>>>(part, gamma, beta, ss);
    k_conv2<<<dim3(256, 8), dim3(256), 0, stream>>>(x, yb, ss, wb2, cb, out);
}

// Round 19
// 313.261 us; speedup vs baseline: 1.3182x; 1.0187x over previous
//
#include <hip/hip_runtime.h>
#include <hip/hip_bf16.h>

// Problem constants
#define BB 8
#define CC 64
#define OO 128
#define HH 128
#define WW 128
#define HW (HH*WW)         // 16384
#define NTAP 9

typedef float f32x4 __attribute__((ext_vector_type(4)));
typedef short short8 __attribute__((ext_vector_type(8)));

__device__ __forceinline__ uint f2bf(float v) {
    uint b = __float_as_uint(v);
    return (b + 0x7FFFu + ((b >> 16) & 1u)) >> 16;   // RNE to bf16
}

__device__ __forceinline__ float sampf(const float* __restrict__ xc, int iy, int ix) {
    // padded-image coords (130x130, zero border of width 1)
    unsigned uy = (unsigned)(iy - 1), ux = (unsigned)(ix - 1);
    return (uy < 128u && ux < 128u) ? xc[uy * 128 + ux] : 0.f;
}

// ---------------------------------------------------------------------------
// Kernel 0: repack weights (validated verbatim).
// ---------------------------------------------------------------------------
__global__ void k_repack(const float* __restrict__ pw, const float* __restrict__ dw,
                         const float* __restrict__ cw,
                         float* __restrict__ wp1, float* __restrict__ wpd,
                         ushort* __restrict__ wb2) {
    int i = blockIdx.x * 256 + threadIdx.x;
    if (i < 10368) {
        int o = i % 18, t = (i / 18) % 9, c = i / 162;
        wp1[i] = pw[(o * 64 + c) * 9 + t];
    }
    if (i < 36864) {
        int o = i % 64, t = (i / 64) % 9, c = i / 576;
        wpd[i] = dw[(o * 64 + c) * 9 + t];
    }
    if (i < 73728) {
        int j = i & 7, lane = (i >> 3) & 63, ot = (i >> 9) & 7;
        int kc = (i >> 12) & 1, t = i >> 13;
        int c = kc * 32 + (lane >> 4) * 8 + j;
        int oc = ot * 16 + (lane & 15);
        wb2[i] = (ushort)f2bf(cw[(oc * 64 + c) * 9 + t]);
    }
}

// ---------------------------------------------------------------------------
// Kernel 1: p_conv — R16-validated verbatim.
// ---------------------------------------------------------------------------
__global__ __launch_bounds__(256) void k_pconv(const float* __restrict__ x,
                                               const float* __restrict__ wp1,
                                               const float* __restrict__ pb,
                                               float* __restrict__ off) {
    int tile = blockIdx.x;                 // 0..127 (16 tile-rows x 8 tile-cols)
    int b = blockIdx.y;
    int ty0 = (tile >> 3) * 8, tx0 = (tile & 7) * 16;
    int tid = threadIdx.x;
    int px = tid & 127;                    // pixel 0..127
    int ch = __builtin_amdgcn_readfirstlane(tid >> 7);  // wave-uniform half 0/1
    int pyr = px >> 4, pxl = px & 15;      // 8 rows x 16 cols

    __shared__ float lx[32][180];          // 32 ch x (10 rows x 18 cols) halo
    __shared__ float pacc[128][19];        // partial acc (padded stride)

    float acc[18];
#pragma unroll
    for (int o = 0; o < 18; o++) acc[o] = 0.f;

    for (int h = 0; h < 2; h++) {
        __syncthreads();                   // h=1: lx free (all reads done)
        for (int idx = tid; idx < 5760; idx += 256) {
            int c = idx / 180, pos = idx % 180;
            int r = pos / 18, col = pos % 18;
            int gy = ty0 + r - 1, gx = tx0 + col - 1;
            float v = 0.f;
            if ((unsigned)gy < 128u && (unsigned)gx < 128u)
                v = x[((b * 64 + h * 32 + c) * 128 + gy) * 128 + gx];
            lx[c][pos] = v;
        }
        __syncthreads();
        for (int ci = 0; ci < 16; ci++) {
            int c = ch * 16 + ci;          // chunk-local channel (wave-uniform)
#pragma unroll
            for (int t = 0; t < 9; t++) {
                float xv = lx[c][(pyr + t / 3) * 18 + pxl + t % 3];
                const float* wr = wp1 + ((h * 32 + c) * 9 + t) * 18;  // s_load
#pragma unroll
                for (int o = 0; o < 18; o++) acc[o] = fmaf(xv, wr[o], acc[o]);
            }
        }
    }
    // ---- deterministic pair-reduction: ch1 -> LDS, ch0 adds + bias + store
    if (ch == 1) {
#pragma unroll
        for (int o = 0; o < 18; o++) pacc[px][o] = acc[o];
    }
    __syncthreads();
    if (ch == 0) {
        int yy = ty0 + pyr, xx = tx0 + pxl;
#pragma unroll
        for (int o = 0; o < 18; o++)
            off[((b * 18 + o) * 128 + yy) * 128 + xx] = acc[o] + pacc[px][o] + pb[o];
    }
}

// ---------------------------------------------------------------------------
// Kernel 2: deformable conv fp32 — R14/R16-validated verbatim.
// ---------------------------------------------------------------------------
__global__ __launch_bounds__(256) void k_deform(const float* __restrict__ x,
                                                const float* __restrict__ off,
                                                const float* __restrict__ wpd,
                                                float* __restrict__ y) {
    int tile = blockIdx.x;                 // 0..255
    int b = blockIdx.y;
    int ty0 = (tile / 16) * 8, tx0 = (tile % 16) * 8;
    int tid = threadIdx.x;

    __shared__ uint   mwin[576];           // packed window offsets; 0xFFFFFFFF = fallback
    __shared__ float4 mwt[576];            // bilinear weights (OOB corners zeroed)
    __shared__ uint   xtile[4 * 256];      // [pair][pos] bf16 c-pairs, window = tile +/- 4
    __shared__ uint   xo[4][580];          // [pair][tap*64+px] bf16 c-pairs

    // ---- Stage A: bilinear metadata (R2/R9/R11-proven math) ----
    for (int e = tid; e < 576; e += 256) {
        int n = e >> 6, p = e & 63;
        int py = p >> 3, px = p & 7;
        int yy = ty0 + py, xx = tx0 + px;
        float offh = off[((b * 18 + n) * 128 + yy) * 128 + xx];
        float offw = off[((b * 18 + 9 + n) * 128 + yy) * 128 + xx];
        float ph = (float)(yy + 1) + (float)(n / 3 - 1) + offh;
        float pw = (float)(xx + 1) + (float)(n % 3 - 1) + offw;
        ph = fminf(fmaxf(ph, 0.f), 129.f);
        pw = fminf(fmaxf(pw, 0.f), 129.f);
        float fh = floorf(ph), fw = floorf(pw);
        int lth = (int)fh, ltw = (int)fw;
        int rbh = min(lth + 1, 129), rbw = min(ltw + 1, 129);
        float dh_l = 1.f + (fh - ph);
        float dh_r = 1.f - ((float)rbh - ph);
        float dw_l = 1.f + (fw - pw);
        float dw_r = 1.f - ((float)rbw - pw);
        int uy0 = lth - 1, ux0 = ltw - 1, uy1 = rbh - 1, ux1 = rbw - 1;
        bool iy0 = (unsigned)uy0 < 128u, ix0 = (unsigned)ux0 < 128u;
        bool iy1 = (unsigned)uy1 < 128u, ix1 = (unsigned)ux1 < 128u;
        float w_lt = (iy0 && ix0) ? dh_l * dw_l : 0.f;
        float w_rb = (iy1 && ix1) ? dh_r * dw_r : 0.f;
        float w_lb = (iy0 && ix1) ? dh_l * dw_r : 0.f;
        float w_rt = (iy1 && ix0) ? dh_r * dw_l : 0.f;
        mwt[e] = make_float4(w_lt, w_rb, w_lb, w_rt);
        int wy0 = uy0 - ty0 + 4, wx0 = ux0 - tx0 + 4;
        int wy1 = uy1 - ty0 + 4, wx1 = ux1 - tx0 + 4;
        uint win = 0xFFFFFFFFu;
        if ((unsigned)wy0 < 16u && (unsigned)wx0 < 16u &&
            (unsigned)wy1 < 16u && (unsigned)wx1 < 16u) {
            uint o00 = (uint)(wy0 * 16 + wx0);
            uint o11 = (uint)(wy1 * 16 + wx1);
            uint o01 = (uint)(wy0 * 16 + wx1);
            uint o10 = (uint)(wy1 * 16 + wx0);
            win = o00 | (o11 << 8) | (o01 << 16) | (o10 << 24);
        }
        mwin[e] = win;
    }

    float acc[16] = {};
    int cg = tid >> 6;                     // wave id = channel-PAIR in gather
    int l64 = tid & 63;                    // lane = pixel in contraction
    int cgoff = cg * 256;
    int ob = __builtin_amdgcn_readfirstlane(cg * 16);  // wave's oc base

    // staging coords for this thread (position = tid)
    int sgy = ty0 - 4 + (tid >> 4), sgx = tx0 - 4 + (tid & 15);
    bool sinb = ((unsigned)sgy < 128u && (unsigned)sgx < 128u);
    int spos = sgy * 128 + sgx;

    for (int cc = 0; cc < 8; cc++) {
        // ---- stage 16x16 window, 8 channels packed as 4 bf16-pairs ----
#pragma unroll
        for (int q = 0; q < 4; q++) {
            int c0 = cc * 8 + 2 * q;
            float v0 = 0.f, v1 = 0.f;
            if (sinb) {
                v0 = x[(size_t)(b * 64 + c0) * HW + spos];
                v1 = x[(size_t)(b * 64 + c0 + 1) * HW + spos];
            }
            xtile[q * 256 + tid] = (f2bf(v1) << 16) | f2bf(v0);
        }
        __syncthreads();                   // xtile staged (prev phases closed)
        // ---- gather: 4 random b32 reads serve 2 channels each ----
#pragma unroll 2
        for (int i = 0; i < 9; i++) {
            int e = l64 + 64 * i;
            uint w = mwin[e];
            float4 g = mwt[e];
            float vlo, vhi;
            if (__builtin_expect(w != 0xFFFFFFFFu, 1)) {
                uint u00 = xtile[cgoff + (w & 255u)];
                uint u11 = xtile[cgoff + ((w >> 8) & 255u)];
                uint u01 = xtile[cgoff + ((w >> 16) & 255u)];
                uint u10 = xtile[cgoff + (w >> 24)];
                float a00l = __uint_as_float(u00 << 16), a00h = __uint_as_float(u00 & 0xFFFF0000u);
                float a11l = __uint_as_float(u11 << 16), a11h = __uint_as_float(u11 & 0xFFFF0000u);
                float a01l = __uint_as_float(u01 << 16), a01h = __uint_as_float(u01 & 0xFFFF0000u);
                float a10l = __uint_as_float(u10 << 16), a10h = __uint_as_float(u10 & 0xFFFF0000u);
                vlo = g.x * a00l + g.y * a11l + g.z * a01l + g.w * a10l;
                vhi = g.x * a00h + g.y * a11h + g.z * a01h + g.w * a10h;
            } else {
                // cold fallback: exact R2 global path for both channels
                int n = e >> 6, p = e & 63;
                int yy2 = ty0 + (p >> 3), xx2 = tx0 + (p & 7);
                float offh = off[((b * 18 + n) * 128 + yy2) * 128 + xx2];
                float offw = off[((b * 18 + 9 + n) * 128 + yy2) * 128 + xx2];
                float ph = fminf(fmaxf((float)(yy2 + 1) + (float)(n / 3 - 1) + offh, 0.f), 129.f);
                float pw = fminf(fmaxf((float)(xx2 + 1) + (float)(n % 3 - 1) + offw, 0.f), 129.f);
                int lth = (int)floorf(ph), ltw = (int)floorf(pw);
                int rbh = min(lth + 1, 129), rbw = min(ltw + 1, 129);
                const float* xc0 = x + (size_t)(b * 64 + cc * 8 + 2 * cg) * HW;
                const float* xc1 = xc0 + HW;
                vlo = g.x * sampf(xc0, lth, ltw) + g.y * sampf(xc0, rbh, rbw)
                    + g.z * sampf(xc0, lth, rbw) + g.w * sampf(xc0, rbh, ltw);
                vhi = g.x * sampf(xc1, lth, ltw) + g.y * sampf(xc1, rbh, rbw)
                    + g.z * sampf(xc1, lth, rbw) + g.w * sampf(xc1, rbh, ltw);
            }
            xo[cg][e] = (f2bf(vhi) << 16) | f2bf(vlo);
        }
        __syncthreads();                   // xo ready
        // ---- contraction: one dword read -> 2 channels x 16 oc FMAs ----
        for (int q = 0; q < 4; q++) {
#pragma unroll
            for (int n = 0; n < 9; n++) {
                uint u = xo[q][n * 64 + l64];
                float xlo = __uint_as_float(u << 16);
                float xhi = __uint_as_float(u & 0xFFFF0000u);
                const float* w0 = wpd + (((cc * 8 + 2 * q) * 9 + n) * 64) + ob;
                const float* w1 = w0 + 576;   // next channel's row
#pragma unroll
                for (int j = 0; j < 16; j++) acc[j] = fmaf(xlo, w0[j], acc[j]);
#pragma unroll
                for (int j = 0; j < 16; j++) acc[j] = fmaf(xhi, w1[j], acc[j]);
            }
        }
        __syncthreads();                   // contraction done before next stage
    }

    // ---- epilogue: direct per-lane stores (lane=pixel, wave's 16 oc) ----
    int yy = ty0 + (l64 >> 3), xx = tx0 + (l64 & 7);
#pragma unroll
    for (int j = 0; j < 16; j++)
        y[(size_t)(b * 64 + ob + j) * HW + yy * 128 + xx] = acc[j];
}

// ---------------------------------------------------------------------------
// Kernel 3a/3b: BN statistics — 4-quarter split (R18-validated).
// ---------------------------------------------------------------------------
__global__ __launch_bounds__(256) void k_bnpart(const float* __restrict__ y,
                                                float* __restrict__ part) {
    int c = blockIdx.x;                    // 0..63
    int bq = blockIdx.y;                   // 0..31
    int b = bq >> 2, hq = bq & 3;
    int tid = threadIdx.x;
    const float4* p = (const float4*)(y + (size_t)(b * 64 + c) * HW + hq * 4096);
    float s = 0.f, sq = 0.f;
    for (int i = tid; i < 1024; i += 256) {
        float4 v = p[i];
        s += v.x + v.y + v.z + v.w;
        sq += v.x * v.x + v.y * v.y + v.z * v.z + v.w * v.w;
    }
#pragma unroll
    for (int o = 32; o > 0; o >>= 1) {
        s += __shfl_down(s, o);
        sq += __shfl_down(sq, o);
    }
    __shared__ float rs[4], rq[4];
    int wid = tid >> 6;
    if ((tid & 63) == 0) { rs[wid] = s; rq[wid] = sq; }
    __syncthreads();
    if (tid == 0) {
        part[((b * 64 + c) * 4 + hq) * 2]     = rs[0] + rs[1] + rs[2] + rs[3];
        part[((b * 64 + c) * 4 + hq) * 2 + 1] = rq[0] + rq[1] + rq[2] + rq[3];
    }
}

__global__ void k_bnfinal(const float* __restrict__ part,
                          const float* __restrict__ gamma,
                          const float* __restrict__ beta,
                          float* __restrict__ ss) {
    int c = threadIdx.x;                   // 64 threads
    float s = 0.f, sq = 0.f;
#pragma unroll
    for (int b = 0; b < 8; b++)
#pragma unroll
        for (int hq = 0; hq < 4; hq++) {
            s += part[((b * 64 + c) * 4 + hq) * 2];
            sq += part[((b * 64 + c) * 4 + hq) * 2 + 1];
        }
    const float inv = 1.f / (float)(8 * HW);
    float mean = s * inv;
    float var = sq * inv - mean * mean;
    float scale = gamma[c] * rsqrtf(var + 1e-5f);
    ss[c] = scale;
    ss[64 + c] = beta[c] - mean * scale;
}

// ---------------------------------------------------------------------------
// Kernel 4: conv2 via MFMA — B-load amortization. Wave now owns ALL 64 px
// x 2 oc-tiles (was 16 px x 8 ot): per (t,kc) the 2 B-frags load ONCE and
// serve 4 pixel-group MFMAs -> weight L2 traffic 1.2GB -> 0.3GB. Staging,
// A-read pos formula and D->store mapping identical to the R5-validated
// code (pixel = pgx*16+r16 for A; store row = jg*4+rr).
// ---------------------------------------------------------------------------
__global__ __launch_bounds__(256) void k_conv2(const float* __restrict__ x,
                                               const float* __restrict__ y,
                                               const float* __restrict__ ss,
                                               const ushort* __restrict__ wb2,
                                               const float* __restrict__ b2,
                                               float* __restrict__ out) {
    int tile = blockIdx.x, b = blockIdx.y;
    int ty0 = (tile / 16) * 8, tx0 = (tile % 16) * 8;
    int tid = threadIdx.x;

    __shared__ uint lz[3600];              // [100 pos][36 dwords] bf16 c-pairs

    for (int idx = tid; idx < 3200; idx += 256) {
        int q = idx / 100, pos = idx % 100;
        int r = pos / 10, col = pos % 10;
        int gy = ty0 + r - 1, gx = tx0 + col - 1;
        uint u = 0;
        if ((unsigned)gy < 128u && (unsigned)gx < 128u) {
            int c0 = q * 2;
            int gi = ((b * 64 + c0) * HW) + gy * 128 + gx;
            float t0 = fmaf(y[gi], ss[c0], ss[64 + c0]);
            float v0 = fmaxf(t0, 0.f) + x[gi];
            float t1 = fmaf(y[gi + HW], ss[c0 + 1], ss[65 + c0]);
            float v1 = fmaxf(t1, 0.f) + x[gi + HW];
            u = (f2bf(v1) << 16) | f2bf(v0);
        }
        lz[pos * 36 + q] = u;
    }
    __syncthreads();

    int lane = tid & 63, wv = tid >> 6;    // wave owns oc-tiles {2wv, 2wv+1}
    int r16 = lane & 15, jg = lane >> 4;

    f32x4 acc[4][2];
#pragma unroll
    for (int otl = 0; otl < 2; otl++) {
        float bv = b2[(2 * wv + otl) * 16 + r16];
#pragma unroll
        for (int pgx = 0; pgx < 4; pgx++)
            acc[pgx][otl] = (f32x4){bv, bv, bv, bv};
    }

#pragma unroll
    for (int t = 0; t < 9; t++) {
#pragma unroll
        for (int kc = 0; kc < 2; kc++) {
            const ushort* wk = wb2 + (t * 2 + kc) * 4096 + lane * 8;
            short8 bv0 = *(const short8*)(wk + (2 * wv) * 512);
            short8 bv1 = *(const short8*)(wk + (2 * wv + 1) * 512);
#pragma unroll
            for (int pgx = 0; pgx < 4; pgx++) {
                int p = pgx * 16 + r16;
                int pos = ((p >> 3) + t / 3) * 10 + ((p & 7) + t % 3);
                short8 av = *(const short8*)(lz + pos * 36 + kc * 16 + jg * 4);
                acc[pgx][0] = __builtin_amdgcn_mfma_f32_16x16x32_bf16(av, bv0, acc[pgx][0], 0, 0, 0);
                acc[pgx][1] = __builtin_amdgcn_mfma_f32_16x16x32_bf16(av, bv1, acc[pgx][1], 0, 0, 0);
            }
        }
    }

    // ---- epilogue: direct per-lane vector stores ----
#pragma unroll
    for (int pgx = 0; pgx < 4; pgx++) {
        int p0 = pgx * 16 + jg * 4;
        int yy = ty0 + (p0 >> 3), xx = tx0 + (p0 & 7);
#pragma unroll
        for (int otl = 0; otl < 2; otl++) {
            int oc = (2 * wv + otl) * 16 + r16;
            *(f32x4*)(out + (size_t)(b * 128 + oc) * HW + yy * 128 + xx) = acc[pgx][otl];
        }
    }
}

// ---------------------------------------------------------------------------
extern "C" void kernel_launch(void* const* d_in, const int* in_sizes, int n_in,
                              void* d_out, int out_size, void* d_ws, size_t ws_size,
                              hipStream_t stream) {
    const float* x     = (const float*)d_in[0];
    const float* pw    = (const float*)d_in[1];
    const float* pb    = (const float*)d_in[2];
    const float* dw    = (const float*)d_in[3];
    const float* gamma = (const float*)d_in[4];
    const float* beta  = (const float*)d_in[5];
    const float* cw    = (const float*)d_in[6];
    const float* cb    = (const float*)d_in[7];
    float* out = (float*)d_out;
    float* ws  = (float*)d_ws;

    // workspace layout (float offsets)
    float*  wp1  = ws;                      // 10368
    float*  ss   = ws + 10368;              // 128
    float*  part = ws + 10496;              // 4096 -> ends 14592
    float*  wpd  = ws + 14592;              // 36864 -> ends 51456
    ushort* wb2  = (ushort*)(ws + 51456);   // 73728 sh (36864 f) -> ends 88320
    float*  off  = ws + 88320;              // 2359296 -> ends 2447616
    float*  yb   = ws + 2447616;            // 8388608 -> ends 10836224
    // total: 10836224 floats = 43.3 MB

    k_repack<<<dim3(288), dim3(256), 0, stream>>>(pw, dw, cw, wp1, wpd, wb2);
    k_pconv<<<dim3(128, 8), dim3(256), 0, stream>>>(x, wp1, pb, off);
    k_deform<<<dim3(256, 8), dim3(256), 0, stream>>>(x, off, wpd, yb);
    k_bnpart<<<dim3(64, 32), dim3(256), 0, stream>>>(yb, part);
    k_bnfinal<<<dim3(1), dim3(64), 0, stream>>>(part, gamma, beta, ss);
    k_conv2<<<dim3(256, 8), dim3(256), 0, stream>>>(x, yb, ss, wb2, cb, out);
}